// Round 9
// baseline (4000.497 us; speedup 1.0000x reference)
//
#include <hip/hip_runtime.h>
#include <stdint.h>
#include <stddef.h>

typedef __bf16 bf16_t;
typedef bf16_t bf16x8 __attribute__((ext_vector_type(8)));
typedef bf16_t bf16x4 __attribute__((ext_vector_type(4)));
typedef float  f32x4  __attribute__((ext_vector_type(4)));

#define T_STEPS 2028
#define SEQ     2048
#define CIN     32
#define NG      32     // batch groups
#define MB      2      // batch per group
#define CH      16     // chunk steps (16: halves pipeline fill vs 32)
#define NCH     127    // ceil(2028/16)
#define RING    4      // ring depth in chunks

// workspace layout (bytes)
#define OFF_EFFW   0u          // bf16 [512][640]  (permuted gate rows)
#define OFF_BIAS   655360u     // f32  [4][512]    (permuted)
#define OFF_WHH    663552u     // bf16 [4][512][128] (permuted)
#define OFF_WIH    1187840u    // bf16 [3][512][128] (permuted, layers 1..3)
#define OFF_CNT    1613824u    // u32  [12][32][16] (64B-strided counters)
#define OFF_XRING  1638400u    // bf16 [4][NG][RING][32][512]
#define OFF_YRING  35192832u   // bf16 [3][NG][RING][32][128]

__device__ __forceinline__ int endk(int k) {
  int e = (k + 1) * CH;
  return e > T_STEPS ? T_STEPS : e;
}

__device__ __forceinline__ void spin_ge(uint32_t* p, uint32_t tgt) {
  while (atomicAdd(p, 0u) < tgt) __builtin_amdgcn_s_sleep(2);
}
__device__ __forceinline__ void publish(uint32_t* p, uint32_t v) {
  __builtin_amdgcn_fence(__ATOMIC_RELEASE, "agent");
  atomicMax(p, v);
}

__device__ __forceinline__ float fsigm(float x) {
  return __builtin_amdgcn_rcpf(1.0f + __builtin_amdgcn_exp2f(x * -1.44269504089f));
}
__device__ __forceinline__ float ftanh(float x) {
  return 1.0f - 2.0f * __builtin_amdgcn_rcpf(1.0f + __builtin_amdgcn_exp2f(x * 2.88539008178f));
}

__device__ __forceinline__ bf16x8 ldg8(const bf16_t* p) { return *(const bf16x8*)p; }
__device__ __forceinline__ bf16x4 ldg4(const bf16_t* p) { return *(const bf16x4*)p; }

__device__ __forceinline__ bf16x8 ldg_cvt8(const float* p) {
  const f32x4 a = *(const f32x4*)p;
  const f32x4 b = *(const f32x4*)(p + 4);
  bf16x8 r;
  r[0] = (bf16_t)a[0]; r[1] = (bf16_t)a[1]; r[2] = (bf16_t)a[2]; r[3] = (bf16_t)a[3];
  r[4] = (bf16_t)b[0]; r[5] = (bf16_t)b[1]; r[6] = (bf16_t)b[2]; r[7] = (bf16_t)b[3];
  return r;
}

// permuted gate row p -> original row: gate = p&3 (i,f,g,o), j = p>>2; orig = gate*128 + j

// ---------------- prep: permute weights, biases, zero counters ----------------
__global__ void k_prep_misc(const float* __restrict__ w_hh0,
                            const float* __restrict__ w_ih_rest,
                            const float* __restrict__ w_hh_rest,
                            const float* __restrict__ b_ih_rest,
                            const float* __restrict__ b_hh_rest,
                            uint8_t* __restrict__ ws) {
  const int bid = blockIdx.x;          // 2048 blocks
  const int l = bid >> 9;              // 0..3
  const int p = bid & 511;
  const int orig = (p & 3) * 128 + (p >> 2);
  const int tid = threadIdx.x;         // 128 threads
  bf16_t* whh = (bf16_t*)(ws + OFF_WHH);
  bf16_t* wih = (bf16_t*)(ws + OFF_WIH);
  float* bias = (float*)(ws + OFF_BIAS);
  const float* src = (l == 0) ? (w_hh0 + orig * 128)
                              : (w_hh_rest + ((size_t)(l - 1) * 512 + orig) * 128);
  whh[((size_t)l * 512 + p) * 128 + tid] = (bf16_t)src[tid];
  if (l < 3)
    wih[((size_t)l * 512 + p) * 128 + tid] = (bf16_t)w_ih_rest[((size_t)l * 512 + orig) * 128 + tid];
  if (l >= 1 && tid == 0)
    bias[l * 512 + p] = b_ih_rest[(l - 1) * 512 + orig] + b_hh_rest[(l - 1) * 512 + orig];
  if (bid == 0) {
    uint32_t* cnt = (uint32_t*)(ws + OFF_CNT);
    for (int i = tid; i < 12 * 32 * 16; i += 128) cnt[i] = 0;
  }
}

// eff_w = w_ih0 @ proj_w (fused proj+layer0-input), eff_b -> bias[0]
__global__ void k_prep_effw(const float* __restrict__ proj_w,
                            const float* __restrict__ proj_b,
                            const float* __restrict__ w_ih0,
                            const float* __restrict__ b_ih0,
                            const float* __restrict__ b_hh0,
                            uint8_t* __restrict__ ws) {
  __shared__ float wr[320];
  const int p = blockIdx.x;            // 512 blocks
  const int orig = (p & 3) * 128 + (p >> 2);
  const int tid = threadIdx.x;         // 256 threads
  for (int i = tid; i < 320; i += 256) wr[i] = w_ih0[(size_t)orig * 320 + i];
  __syncthreads();
  bf16_t* effw = (bf16_t*)(ws + OFF_EFFW);
  for (int kk = tid; kk < 640; kk += 256) {
    float a = 0.f;
    for (int z = 0; z < 320; ++z) a += wr[z] * proj_w[(size_t)z * 640 + kk];
    effw[(size_t)p * 640 + kk] = (bf16_t)a;
  }
  if (tid == 0) {
    float a = 0.f;
    for (int z = 0; z < 320; ++z) a += wr[z] * proj_b[z];
    ((float*)(ws + OFF_BIAS))[p] = a + b_ih0[orig] + b_hh0[orig];
  }
}

// ---------------- the 8-stage persistent pipeline ----------------
// 256 threads = 4 waves (1 wave/SIMD — measured best across {2,4,8}).
// Per-step sync: lgkm-only s_barrier (measured equal to LDS-flag sync).
// stage s = blockIdx.x>>5 : 0=conv, 1..4=recur l=s-1, 5..7=gemm l=s-4 ; g = blockIdx.x&31
__global__ __launch_bounds__(256, 1) void k_pipeline(const float* __restrict__ in,
                                                     const float* __restrict__ out_w,
                                                     const float* __restrict__ out_b,
                                                     float* __restrict__ out,
                                                     uint8_t* __restrict__ ws) {
  __shared__ __align__(16) bf16_t h_lds[2][16][136];
  __shared__ f32x4 gate_buf[4][2][32];
  __shared__ float hfl[2][128];        // final h (f32) for the fused output head

  const int s = blockIdx.x >> 5;
  const int g = blockIdx.x & 31;
  const int tid = threadIdx.x;
  const int lane = tid & 63;
  const int w = tid >> 6;              // wave 0..3
  const int q = lane >> 4;             // 0..3
  const int ln = lane & 15;

  uint32_t* cnt = (uint32_t*)(ws + OFF_CNT);
  bf16_t* xring = (bf16_t*)(ws + OFF_XRING);
  bf16_t* yring = (bf16_t*)(ws + OFF_YRING);

  if (s == 0) {
    // ---- conv stage: windows(inputs) @ eff_w^T -> x_ring[0] ----
    const bf16_t* effw = (const bf16_t*)(ws + OFF_EFFW);
    uint32_t* my = cnt + (0 * NG + g) * 16;
    uint32_t* guard = cnt + (1 * NG + g) * 16;   // recur0 progress (ring free)
    for (int k = 0; k < NCH; ++k) {
      if (tid == 0 && k >= RING) spin_ge(guard, (uint32_t)endk(k - RING));
      __syncthreads();
      const int t0 = k * CH;
      f32x4 acc[2][8];
#pragma unroll
      for (int mt = 0; mt < 2; ++mt)
#pragma unroll
        for (int nt = 0; nt < 8; ++nt) acc[mt][nt] = (f32x4){0.f, 0.f, 0.f, 0.f};
#pragma unroll
      for (int kt = 0; kt < 20; ++kt) {          // kt == window offset
        bf16x8 bfr[8];
#pragma unroll
        for (int nt = 0; nt < 8; ++nt)
          bfr[nt] = ldg8(effw + (size_t)((w * 8 + nt) * 16 + ln) * 640 + kt * 32 + q * 8);
#pragma unroll
        for (int mt = 0; mt < 2; ++mt) {
          int m = mt * 16 + ln;                  // 0..31 = step*2 + batch
          int trel = m >> 1, bb = m & 1;
          int tt = t0 + trel; if (tt > T_STEPS - 1) tt = T_STEPS - 1;
          bf16x8 afr = ldg_cvt8(in + (size_t)((g * MB + bb) * SEQ + tt + kt) * CIN + q * 8);
#pragma unroll
          for (int nt = 0; nt < 8; ++nt)
            acc[mt][nt] = __builtin_amdgcn_mfma_f32_16x16x32_bf16(afr, bfr[nt], acc[mt][nt], 0, 0, 0);
        }
      }
      bf16_t* xs = xring + (size_t)((0 * NG + g) * RING + (k & 3)) * (32 * 512);
#pragma unroll
      for (int mt = 0; mt < 2; ++mt)
#pragma unroll
        for (int nt = 0; nt < 8; ++nt)
#pragma unroll
          for (int r = 0; r < 4; ++r)
            xs[(size_t)(mt * 16 + q * 4 + r) * 512 + (w * 8 + nt) * 16 + ln] = (bf16_t)acc[mt][nt][r];
      __syncthreads();
      if (tid == 0) publish(my, (uint32_t)endk(k));
    }
  } else if (s <= 4) {
    // ---- recurrent stage, layer l ----
    const int l = s - 1;
    const bf16_t* whh = (const bf16_t*)(ws + OFF_WHH) + (size_t)l * 512 * 128;
    bf16x8 wfr[8][4];                            // A = w_hh rows (gates), step-invariant
#pragma unroll
    for (int mt = 0; mt < 8; ++mt)
#pragma unroll
      for (int kt = 0; kt < 4; ++kt)
        wfr[mt][kt] = ldg8(whh + (size_t)(w * 128 + mt * 16 + ln) * 128 + kt * 32 + q * 8);
    const int b_ep = lane >> 5;                  // 0..1
    const int j_loc = lane & 31;                 // 0..31
    const int jg = w * 32 + j_loc;               // 0..127
    f32x4 biasq = *(const f32x4*)((const float*)(ws + OFF_BIAS) + l * 512 + 4 * jg);
    float c = 0.f;
    {
      bf16_t* hz = &h_lds[0][0][0];
      for (int i = tid; i < 2 * 16 * 136; i += 256) hz[i] = (bf16_t)0.f;
    }
    __syncthreads();
    uint32_t* my = cnt + ((1 + l) * NG + g) * 16;
    uint32_t* prod = (l == 0) ? (cnt + (0 * NG + g) * 16) : (cnt + ((4 + l) * NG + g) * 16);
    uint32_t* yguard = cnt + ((5 + l) * NG + g) * 16;  // gemm_{l+1}; only spun when l<3
    const int ly = (l < 3) ? l : 0;

    for (int k = 0; k < NCH; ++k) {
      const int t0 = k * CH;
      const int tlen = (T_STEPS - t0 < CH) ? (T_STEPS - t0) : CH;
      if (tid == 0) {
        spin_ge(prod, (uint32_t)(t0 + tlen));
        if (l < 3 && k >= RING) spin_ge(yguard, (uint32_t)endk(k - RING));
        __builtin_amdgcn_fence(__ATOMIC_ACQUIRE, "agent");
      }
      __syncthreads();
      const bf16_t* xlane = xring + (size_t)((l * NG + g) * RING + (k & 3)) * (32 * 512)
                            + b_ep * 512 + 4 * jg;
      bf16_t* ylane = yring + (size_t)((ly * NG + g) * RING + (k & 3)) * (32 * 128)
                      + b_ep * 128 + jg;

      if (tlen == CH) {
        // ---- fast path: 16 steps, inner loop VMEM-free ----
        bf16x4 xq[16];
#pragma unroll
        for (int t = 0; t < 16; ++t) xq[t] = ldg4(xlane + (size_t)t * 1024);
        bf16_t yv[16];
#pragma unroll
        for (int t = 0; t < 16; ++t) {
          const int buf = (t0 + t) & 1;
          f32x4 acc[8];
#pragma unroll
          for (int mt = 0; mt < 8; ++mt) acc[mt] = (f32x4){0.f, 0.f, 0.f, 0.f};
#pragma unroll
          for (int kt = 0; kt < 3; ++kt) {
            bf16x8 hk = *(const bf16x8*)&h_lds[buf][ln][kt * 32 + q * 8];
#pragma unroll
            for (int mt = 0; mt < 8; ++mt)
              acc[mt] = __builtin_amdgcn_mfma_f32_16x16x32_bf16(wfr[mt][kt], hk, acc[mt], 0, 0, 0);
          }
          {
            bf16x8 hk3 = *(const bf16x8*)&h_lds[buf][ln][3 * 32 + q * 8];
#pragma unroll
            for (int mt = 0; mt < 8; ++mt) {
              acc[mt] = __builtin_amdgcn_mfma_f32_16x16x32_bf16(wfr[mt][3], hk3, acc[mt], 0, 0, 0);
              if (ln < MB) gate_buf[w][ln][mt * 4 + q] = acc[mt];
            }
          }
          f32x4 gq = gate_buf[w][b_ep][j_loc];   // intra-wave LDS bounce
          float gi = fsigm(gq[0] + (float)xq[t][0] + biasq[0]);
          float gf = fsigm(gq[1] + (float)xq[t][1] + biasq[1]);
          float gg = ftanh(gq[2] + (float)xq[t][2] + biasq[2]);
          float go = fsigm(gq[3] + (float)xq[t][3] + biasq[3]);
          c = gf * c + gi * gg;
          float hv = go * ftanh(c);
          h_lds[buf ^ 1][b_ep][jg] = (bf16_t)hv;
          yv[t] = (bf16_t)hv;
          asm volatile("s_waitcnt lgkmcnt(0)\n\ts_barrier" ::: "memory");
        }
        if (l < 3) {
#pragma unroll
          for (int t = 0; t < 16; ++t)
            ylane[(size_t)t * 256] = yv[t];
        }
      } else {
        // ---- tail path (last chunk, 12 steps) ----
        for (int trel = 0; trel < tlen; ++trel) {
          const int t = t0 + trel;
          const int buf = t & 1;
          bf16x4 xqs = ldg4(xlane + (size_t)trel * 1024);
          f32x4 acc[8];
#pragma unroll
          for (int mt = 0; mt < 8; ++mt) acc[mt] = (f32x4){0.f, 0.f, 0.f, 0.f};
#pragma unroll
          for (int kt = 0; kt < 4; ++kt) {
            bf16x8 hk = *(const bf16x8*)&h_lds[buf][ln][kt * 32 + q * 8];
#pragma unroll
            for (int mt = 0; mt < 8; ++mt)
              acc[mt] = __builtin_amdgcn_mfma_f32_16x16x32_bf16(wfr[mt][kt], hk, acc[mt], 0, 0, 0);
          }
          if (ln < MB) {
#pragma unroll
            for (int mt = 0; mt < 8; ++mt)
              gate_buf[w][ln][mt * 4 + q] = acc[mt];
          }
          f32x4 gq = gate_buf[w][b_ep][j_loc];
          float gi = fsigm(gq[0] + (float)xqs[0] + biasq[0]);
          float gf = fsigm(gq[1] + (float)xqs[1] + biasq[1]);
          float gg = ftanh(gq[2] + (float)xqs[2] + biasq[2]);
          float go = fsigm(gq[3] + (float)xqs[3] + biasq[3]);
          c = gf * c + gi * gg;
          float hv = go * ftanh(c);
          h_lds[buf ^ 1][b_ep][jg] = (bf16_t)hv;
          if (l < 3) ylane[(size_t)trel * 256] = (bf16_t)hv;
          if (l == 3 && t == T_STEPS - 1) hfl[b_ep][jg] = hv;   // f32 h -> LDS
          asm volatile("s_waitcnt lgkmcnt(0)\n\ts_barrier" ::: "memory");
        }
      }
      __syncthreads();   // drains vmcnt in every wave before publishing
      if (tid == 0) publish(my, (uint32_t)(t0 + tlen));
    }

    // ---- fused output head (layer-3 blocks only): out = h_fin @ out_w^T + out_b ----
    if (l == 3) {
      __syncthreads();                 // hfl visible to all waves
      if (tid < 96) {                  // 2 batches x 48 outputs per group
        const int b_loc = tid / 48, o = tid % 48;
        const float* wrow = out_w + (size_t)o * 128;
        float a = out_b[o];
#pragma unroll 4
        for (int j = 0; j < 128; ++j) a += hfl[b_loc][j] * wrow[j];
        out[(size_t)(g * MB + b_loc) * 48 + o] = a;
      }
    }
  } else {
    // ---- gemm stage: x_pre_l = y_{l-1} @ w_ih_l^T, l = s-4 in 1..3 ----
    const int l = s - 4;
    const bf16_t* wih = (const bf16_t*)(ws + OFF_WIH) + (size_t)(l - 1) * 512 * 128;
    bf16x8 bfr[8][4];
#pragma unroll
    for (int nt = 0; nt < 8; ++nt)
#pragma unroll
      for (int kt = 0; kt < 4; ++kt)
        bfr[nt][kt] = ldg8(wih + (size_t)((w * 8 + nt) * 16 + ln) * 128 + kt * 32 + q * 8);
    uint32_t* my = cnt + ((4 + l) * NG + g) * 16;
    uint32_t* prod = cnt + (l * NG + g) * 16;         // recur_{l-1} progress
    uint32_t* xguard = cnt + ((1 + l) * NG + g) * 16; // recur_l progress (ring free)
    for (int k = 0; k < NCH; ++k) {
      if (tid == 0) {
        spin_ge(prod, (uint32_t)endk(k));
        if (k >= RING) spin_ge(xguard, (uint32_t)endk(k - RING));
        __builtin_amdgcn_fence(__ATOMIC_ACQUIRE, "agent");
      }
      __syncthreads();
      const bf16_t* ys = yring + (size_t)(((l - 1) * NG + g) * RING + (k & 3)) * (32 * 128);
      bf16_t* xs = xring + (size_t)((l * NG + g) * RING + (k & 3)) * (32 * 512);
      bf16x8 afr[2][4];
#pragma unroll
      for (int mt = 0; mt < 2; ++mt)
#pragma unroll
        for (int kt = 0; kt < 4; ++kt)
          afr[mt][kt] = ldg8(ys + (size_t)(mt * 16 + ln) * 128 + kt * 32 + q * 8);
#pragma unroll
      for (int mt = 0; mt < 2; ++mt) {
        f32x4 a8[8];
#pragma unroll
        for (int nt = 0; nt < 8; ++nt) a8[nt] = (f32x4){0.f, 0.f, 0.f, 0.f};
#pragma unroll
        for (int kt = 0; kt < 4; ++kt) {
#pragma unroll
          for (int nt = 0; nt < 8; ++nt)
            a8[nt] = __builtin_amdgcn_mfma_f32_16x16x32_bf16(afr[mt][kt], bfr[nt][kt], a8[nt], 0, 0, 0);
        }
#pragma unroll
        for (int nt = 0; nt < 8; ++nt)
#pragma unroll
          for (int r = 0; r < 4; ++r)
            xs[(size_t)(mt * 16 + q * 4 + r) * 512 + (w * 8 + nt) * 16 + ln] = (bf16_t)a8[nt][r];
      }
      __syncthreads();
      if (tid == 0) publish(my, (uint32_t)endk(k));
    }
  }
}

extern "C" void kernel_launch(void* const* d_in, const int* in_sizes, int n_in,
                              void* d_out, int out_size, void* d_ws, size_t ws_size,
                              hipStream_t stream) {
  (void)in_sizes; (void)n_in; (void)out_size; (void)ws_size;
  const float* inputs    = (const float*)d_in[0];
  const float* proj_w    = (const float*)d_in[4];
  const float* proj_b    = (const float*)d_in[5];
  const float* w_ih0     = (const float*)d_in[6];
  const float* w_hh0     = (const float*)d_in[7];
  const float* b_ih0     = (const float*)d_in[8];
  const float* b_hh0     = (const float*)d_in[9];
  const float* w_ih_rest = (const float*)d_in[10];
  const float* w_hh_rest = (const float*)d_in[11];
  const float* b_ih_rest = (const float*)d_in[12];
  const float* b_hh_rest = (const float*)d_in[13];
  const float* out_w     = (const float*)d_in[14];
  const float* out_b     = (const float*)d_in[15];
  uint8_t* ws = (uint8_t*)d_ws;
  float* out = (float*)d_out;

  k_prep_misc<<<dim3(2048), dim3(128), 0, stream>>>(w_hh0, w_ih_rest, w_hh_rest,
                                                    b_ih_rest, b_hh_rest, ws);
  k_prep_effw<<<dim3(512), dim3(256), 0, stream>>>(proj_w, proj_b, w_ih0, b_ih0, b_hh0, ws);
  k_pipeline<<<dim3(256), dim3(256), 0, stream>>>(inputs, out_w, out_b, out, ws);
}

// Round 10
// 2734.378 us; speedup vs baseline: 1.4630x; 1.4630x over previous
//
#include <hip/hip_runtime.h>
#include <stdint.h>
#include <stddef.h>

typedef __bf16 bf16_t;
typedef bf16_t bf16x8 __attribute__((ext_vector_type(8)));
typedef bf16_t bf16x4 __attribute__((ext_vector_type(4)));
typedef float  f32x4  __attribute__((ext_vector_type(4)));

#define T_STEPS 2028
#define SEQ     2048
#define CIN     32
#define NG      32     // batch groups
#define MB      2      // batch per group
#define CH      32     // chunk steps (32 measured optimal; 16 = +45% from handoff overhead)
#define NCH     64     // ceil(2028/32)
#define RING    4      // ring depth in chunks

// workspace layout (bytes); total ~41.5 MB
#define OFF_EFFW   0u          // bf16 [512][640]  (permuted gate rows)
#define OFF_BIAS   655360u     // f32  [4][512]    (permuted)
#define OFF_WHH    663552u     // bf16 [4][512][128] (permuted)
#define OFF_WIH    1187840u    // bf16 [3][512][128] (permuted, layers 1..3)
#define OFF_CNT    1613824u    // u32  [12][32][16] (64B-strided counters)
#define OFF_XRING  1638400u    // bf16 [4][NG][RING][64][512]
#define OFF_YRING  35192832u   // bf16 [3][NG][RING][64][128]

__device__ __forceinline__ int endk(int k) {
  int e = (k + 1) * CH;
  return e > T_STEPS ? T_STEPS : e;
}

__device__ __forceinline__ void spin_ge(uint32_t* p, uint32_t tgt) {
  while (atomicAdd(p, 0u) < tgt) __builtin_amdgcn_s_sleep(2);
}
__device__ __forceinline__ void publish(uint32_t* p, uint32_t v) {
  __builtin_amdgcn_fence(__ATOMIC_RELEASE, "agent");
  atomicMax(p, v);
}

__device__ __forceinline__ float fsigm(float x) {
  return __builtin_amdgcn_rcpf(1.0f + __builtin_amdgcn_exp2f(x * -1.44269504089f));
}
__device__ __forceinline__ float ftanh(float x) {
  return 1.0f - 2.0f * __builtin_amdgcn_rcpf(1.0f + __builtin_amdgcn_exp2f(x * 2.88539008178f));
}

__device__ __forceinline__ bf16x8 ldg8(const bf16_t* p) { return *(const bf16x8*)p; }
__device__ __forceinline__ bf16x4 ldg4(const bf16_t* p) { return *(const bf16x4*)p; }

__device__ __forceinline__ bf16x8 ldg_cvt8(const float* p) {
  const f32x4 a = *(const f32x4*)p;
  const f32x4 b = *(const f32x4*)(p + 4);
  bf16x8 r;
  r[0] = (bf16_t)a[0]; r[1] = (bf16_t)a[1]; r[2] = (bf16_t)a[2]; r[3] = (bf16_t)a[3];
  r[4] = (bf16_t)b[0]; r[5] = (bf16_t)b[1]; r[6] = (bf16_t)b[2]; r[7] = (bf16_t)b[3];
  return r;
}

// permuted gate row p -> original row: gate = p&3 (i,f,g,o), j = p>>2; orig = gate*128 + j

// ---------------- prep: permute weights, biases, zero counters ----------------
__global__ void k_prep_misc(const float* __restrict__ w_hh0,
                            const float* __restrict__ w_ih_rest,
                            const float* __restrict__ w_hh_rest,
                            const float* __restrict__ b_ih_rest,
                            const float* __restrict__ b_hh_rest,
                            uint8_t* __restrict__ ws) {
  const int bid = blockIdx.x;          // 2048 blocks
  const int l = bid >> 9;              // 0..3
  const int p = bid & 511;
  const int orig = (p & 3) * 128 + (p >> 2);
  const int tid = threadIdx.x;         // 128 threads
  bf16_t* whh = (bf16_t*)(ws + OFF_WHH);
  bf16_t* wih = (bf16_t*)(ws + OFF_WIH);
  float* bias = (float*)(ws + OFF_BIAS);
  const float* src = (l == 0) ? (w_hh0 + orig * 128)
                              : (w_hh_rest + ((size_t)(l - 1) * 512 + orig) * 128);
  whh[((size_t)l * 512 + p) * 128 + tid] = (bf16_t)src[tid];
  if (l < 3)
    wih[((size_t)l * 512 + p) * 128 + tid] = (bf16_t)w_ih_rest[((size_t)l * 512 + orig) * 128 + tid];
  if (l >= 1 && tid == 0)
    bias[l * 512 + p] = b_ih_rest[(l - 1) * 512 + orig] + b_hh_rest[(l - 1) * 512 + orig];
  if (bid == 0) {
    uint32_t* cnt = (uint32_t*)(ws + OFF_CNT);
    for (int i = tid; i < 12 * 32 * 16; i += 128) cnt[i] = 0;
  }
}

// eff_w = w_ih0 @ proj_w (fused proj+layer0-input), eff_b -> bias[0]
__global__ void k_prep_effw(const float* __restrict__ proj_w,
                            const float* __restrict__ proj_b,
                            const float* __restrict__ w_ih0,
                            const float* __restrict__ b_ih0,
                            const float* __restrict__ b_hh0,
                            uint8_t* __restrict__ ws) {
  __shared__ float wr[320];
  const int p = blockIdx.x;            // 512 blocks
  const int orig = (p & 3) * 128 + (p >> 2);
  const int tid = threadIdx.x;         // 256 threads
  for (int i = tid; i < 320; i += 256) wr[i] = w_ih0[(size_t)orig * 320 + i];
  __syncthreads();
  bf16_t* effw = (bf16_t*)(ws + OFF_EFFW);
  for (int kk = tid; kk < 640; kk += 256) {
    float a = 0.f;
    for (int z = 0; z < 320; ++z) a += wr[z] * proj_w[(size_t)z * 640 + kk];
    effw[(size_t)p * 640 + kk] = (bf16_t)a;
  }
  if (tid == 0) {
    float a = 0.f;
    for (int z = 0; z < 320; ++z) a += wr[z] * proj_b[z];
    ((float*)(ws + OFF_BIAS))[p] = a + b_ih0[orig] + b_hh0[orig];
  }
}

// ---------------- the 8-stage persistent pipeline ----------------
// 256 threads = 4 waves (1 wave/SIMD — measured best across {2,4,8}).
// Per-step sync: lgkm-only s_barrier (measured equal to LDS-flag sync).
// stage s = blockIdx.x>>5 : 0=conv, 1..4=recur l=s-1, 5..7=gemm l=s-4 ; g = blockIdx.x&31
__global__ __launch_bounds__(256, 1) void k_pipeline(const float* __restrict__ in,
                                                     const float* __restrict__ out_w,
                                                     const float* __restrict__ out_b,
                                                     float* __restrict__ out,
                                                     uint8_t* __restrict__ ws) {
  __shared__ __align__(16) bf16_t h_lds[2][16][136];
  __shared__ f32x4 gate_buf[4][2][32];
  __shared__ float hfl[2][128];        // final h (f32) for the fused output head

  const int s = blockIdx.x >> 5;
  const int g = blockIdx.x & 31;
  const int tid = threadIdx.x;
  const int lane = tid & 63;
  const int w = tid >> 6;              // wave 0..3
  const int q = lane >> 4;             // 0..3
  const int ln = lane & 15;

  uint32_t* cnt = (uint32_t*)(ws + OFF_CNT);
  bf16_t* xring = (bf16_t*)(ws + OFF_XRING);
  bf16_t* yring = (bf16_t*)(ws + OFF_YRING);

  if (s == 0) {
    // ---- conv stage: windows(inputs) @ eff_w^T -> x_ring[0] ----
    const bf16_t* effw = (const bf16_t*)(ws + OFF_EFFW);
    uint32_t* my = cnt + (0 * NG + g) * 16;
    uint32_t* guard = cnt + (1 * NG + g) * 16;   // recur0 progress (ring free)
    for (int k = 0; k < NCH; ++k) {
      if (tid == 0 && k >= RING) spin_ge(guard, (uint32_t)endk(k - RING));
      __syncthreads();
      const int t0 = k * CH;
      f32x4 acc[4][8];
#pragma unroll
      for (int mt = 0; mt < 4; ++mt)
#pragma unroll
        for (int nt = 0; nt < 8; ++nt) acc[mt][nt] = (f32x4){0.f, 0.f, 0.f, 0.f};
#pragma unroll
      for (int kt = 0; kt < 20; ++kt) {          // kt == window offset
        bf16x8 bfr[8];
#pragma unroll
        for (int nt = 0; nt < 8; ++nt)
          bfr[nt] = ldg8(effw + (size_t)((w * 8 + nt) * 16 + ln) * 640 + kt * 32 + q * 8);
#pragma unroll
        for (int mt = 0; mt < 4; ++mt) {
          int m = mt * 16 + ln;
          int trel = m >> 1, bb = m & 1;
          int tt = t0 + trel; if (tt > T_STEPS - 1) tt = T_STEPS - 1;
          bf16x8 afr = ldg_cvt8(in + (size_t)((g * MB + bb) * SEQ + tt + kt) * CIN + q * 8);
#pragma unroll
          for (int nt = 0; nt < 8; ++nt)
            acc[mt][nt] = __builtin_amdgcn_mfma_f32_16x16x32_bf16(afr, bfr[nt], acc[mt][nt], 0, 0, 0);
        }
      }
      bf16_t* xs = xring + (size_t)((0 * NG + g) * RING + (k & 3)) * (64 * 512);
#pragma unroll
      for (int mt = 0; mt < 4; ++mt)
#pragma unroll
        for (int nt = 0; nt < 8; ++nt)
#pragma unroll
          for (int r = 0; r < 4; ++r)
            xs[(size_t)(mt * 16 + q * 4 + r) * 512 + (w * 8 + nt) * 16 + ln] = (bf16_t)acc[mt][nt][r];
      __syncthreads();
      if (tid == 0) publish(my, (uint32_t)endk(k));
    }
  } else if (s <= 4) {
    // ---- recurrent stage, layer l ----
    const int l = s - 1;
    const bf16_t* whh = (const bf16_t*)(ws + OFF_WHH) + (size_t)l * 512 * 128;
    bf16x8 wfr[8][4];                            // A = w_hh rows (gates), step-invariant
#pragma unroll
    for (int mt = 0; mt < 8; ++mt)
#pragma unroll
      for (int kt = 0; kt < 4; ++kt)
        wfr[mt][kt] = ldg8(whh + (size_t)(w * 128 + mt * 16 + ln) * 128 + kt * 32 + q * 8);
    const int b_ep = lane >> 5;                  // 0..1
    const int j_loc = lane & 31;                 // 0..31
    const int jg = w * 32 + j_loc;               // 0..127
    f32x4 biasq = *(const f32x4*)((const float*)(ws + OFF_BIAS) + l * 512 + 4 * jg);
    float c = 0.f;
    {
      bf16_t* hz = &h_lds[0][0][0];
      for (int i = tid; i < 2 * 16 * 136; i += 256) hz[i] = (bf16_t)0.f;
    }
    __syncthreads();
    uint32_t* my = cnt + ((1 + l) * NG + g) * 16;
    uint32_t* prod = (l == 0) ? (cnt + (0 * NG + g) * 16) : (cnt + ((4 + l) * NG + g) * 16);
    uint32_t* yguard = cnt + ((5 + l) * NG + g) * 16;  // gemm_{l+1}; only spun when l<3
    const int ly = (l < 3) ? l : 0;

    for (int k = 0; k < NCH; ++k) {
      const int t0 = k * CH;
      const int tlen = (T_STEPS - t0 < CH) ? (T_STEPS - t0) : CH;
      if (tid == 0) {
        spin_ge(prod, (uint32_t)(t0 + tlen));
        if (l < 3 && k >= RING) spin_ge(yguard, (uint32_t)endk(k - RING));
        __builtin_amdgcn_fence(__ATOMIC_ACQUIRE, "agent");
      }
      __syncthreads();
      const bf16_t* xlane = xring + (size_t)((l * NG + g) * RING + (k & 3)) * (64 * 512)
                            + b_ep * 512 + 4 * jg;
      bf16_t* ylane = yring + (size_t)((ly * NG + g) * RING + (k & 3)) * (64 * 128)
                      + b_ep * 128 + jg;

      if (tlen == CH) {
        // ---- fast path: two 16-step halves, inner loop completely VMEM-free ----
        for (int half = 0; half < 2; ++half) {
          const int tb = t0 + half * 16;
          bf16x4 xq[16];
#pragma unroll
          for (int t = 0; t < 16; ++t) xq[t] = ldg4(xlane + (size_t)(half * 16 + t) * 1024);
          bf16_t yv[16];
#pragma unroll
          for (int t = 0; t < 16; ++t) {
            const int buf = (tb + t) & 1;
            f32x4 acc[8];
#pragma unroll
            for (int mt = 0; mt < 8; ++mt) acc[mt] = (f32x4){0.f, 0.f, 0.f, 0.f};
#pragma unroll
            for (int kt = 0; kt < 3; ++kt) {
              bf16x8 hk = *(const bf16x8*)&h_lds[buf][ln][kt * 32 + q * 8];
#pragma unroll
              for (int mt = 0; mt < 8; ++mt)
                acc[mt] = __builtin_amdgcn_mfma_f32_16x16x32_bf16(wfr[mt][kt], hk, acc[mt], 0, 0, 0);
            }
            {
              bf16x8 hk3 = *(const bf16x8*)&h_lds[buf][ln][3 * 32 + q * 8];
#pragma unroll
              for (int mt = 0; mt < 8; ++mt) {
                acc[mt] = __builtin_amdgcn_mfma_f32_16x16x32_bf16(wfr[mt][3], hk3, acc[mt], 0, 0, 0);
                if (ln < MB) gate_buf[w][ln][mt * 4 + q] = acc[mt];
              }
            }
            f32x4 gq = gate_buf[w][b_ep][j_loc];   // intra-wave LDS bounce
            float gi = fsigm(gq[0] + (float)xq[t][0] + biasq[0]);
            float gf = fsigm(gq[1] + (float)xq[t][1] + biasq[1]);
            float gg = ftanh(gq[2] + (float)xq[t][2] + biasq[2]);
            float go = fsigm(gq[3] + (float)xq[t][3] + biasq[3]);
            c = gf * c + gi * gg;
            float hv = go * ftanh(c);
            h_lds[buf ^ 1][b_ep][jg] = (bf16_t)hv;
            yv[t] = (bf16_t)hv;
            asm volatile("s_waitcnt lgkmcnt(0)\n\ts_barrier" ::: "memory");
          }
          if (l < 3) {
#pragma unroll
            for (int t = 0; t < 16; ++t)
              ylane[(size_t)(half * 16 + t) * 256] = yv[t];
          }
        }
      } else {
        // ---- tail path (last chunk, 12 steps) ----
        for (int trel = 0; trel < tlen; ++trel) {
          const int t = t0 + trel;
          const int buf = t & 1;
          bf16x4 xqs = ldg4(xlane + (size_t)trel * 1024);
          f32x4 acc[8];
#pragma unroll
          for (int mt = 0; mt < 8; ++mt) acc[mt] = (f32x4){0.f, 0.f, 0.f, 0.f};
#pragma unroll
          for (int kt = 0; kt < 4; ++kt) {
            bf16x8 hk = *(const bf16x8*)&h_lds[buf][ln][kt * 32 + q * 8];
#pragma unroll
            for (int mt = 0; mt < 8; ++mt)
              acc[mt] = __builtin_amdgcn_mfma_f32_16x16x32_bf16(wfr[mt][kt], hk, acc[mt], 0, 0, 0);
          }
          if (ln < MB) {
#pragma unroll
            for (int mt = 0; mt < 8; ++mt)
              gate_buf[w][ln][mt * 4 + q] = acc[mt];
          }
          f32x4 gq = gate_buf[w][b_ep][j_loc];
          float gi = fsigm(gq[0] + (float)xqs[0] + biasq[0]);
          float gf = fsigm(gq[1] + (float)xqs[1] + biasq[1]);
          float gg = ftanh(gq[2] + (float)xqs[2] + biasq[2]);
          float go = fsigm(gq[3] + (float)xqs[3] + biasq[3]);
          c = gf * c + gi * gg;
          float hv = go * ftanh(c);
          h_lds[buf ^ 1][b_ep][jg] = (bf16_t)hv;
          if (l < 3) ylane[(size_t)trel * 256] = (bf16_t)hv;
          if (l == 3 && t == T_STEPS - 1) hfl[b_ep][jg] = hv;   // f32 h -> LDS
          asm volatile("s_waitcnt lgkmcnt(0)\n\ts_barrier" ::: "memory");
        }
      }
      __syncthreads();   // drains vmcnt in every wave before publishing
      if (tid == 0) publish(my, (uint32_t)(t0 + tlen));
    }

    // ---- fused output head (layer-3 blocks only): out = h_fin @ out_w^T + out_b ----
    if (l == 3) {
      __syncthreads();                 // hfl visible to all waves
      if (tid < 96) {                  // 2 batches x 48 outputs per group
        const int b_loc = tid / 48, o = tid % 48;
        const float* wrow = out_w + (size_t)o * 128;
        float a = out_b[o];
#pragma unroll 4
        for (int j = 0; j < 128; ++j) a += hfl[b_loc][j] * wrow[j];
        out[(size_t)(g * MB + b_loc) * 48 + o] = a;
      }
    }
  } else {
    // ---- gemm stage: x_pre_l = y_{l-1} @ w_ih_l^T, l = s-4 in 1..3 ----
    const int l = s - 4;
    const bf16_t* wih = (const bf16_t*)(ws + OFF_WIH) + (size_t)(l - 1) * 512 * 128;
    bf16x8 bfr[8][4];
#pragma unroll
    for (int nt = 0; nt < 8; ++nt)
#pragma unroll
      for (int kt = 0; kt < 4; ++kt)
        bfr[nt][kt] = ldg8(wih + (size_t)((w * 8 + nt) * 16 + ln) * 128 + kt * 32 + q * 8);
    uint32_t* my = cnt + ((4 + l) * NG + g) * 16;
    uint32_t* prod = cnt + (l * NG + g) * 16;         // recur_{l-1} progress
    uint32_t* xguard = cnt + ((1 + l) * NG + g) * 16; // recur_l progress (ring free)
    for (int k = 0; k < NCH; ++k) {
      if (tid == 0) {
        spin_ge(prod, (uint32_t)endk(k));
        if (k >= RING) spin_ge(xguard, (uint32_t)endk(k - RING));
        __builtin_amdgcn_fence(__ATOMIC_ACQUIRE, "agent");
      }
      __syncthreads();
      const bf16_t* ys = yring + (size_t)(((l - 1) * NG + g) * RING + (k & 3)) * (64 * 128);
      bf16_t* xs = xring + (size_t)((l * NG + g) * RING + (k & 3)) * (64 * 512);
      bf16x8 afr[4][4];
#pragma unroll
      for (int mt = 0; mt < 4; ++mt)
#pragma unroll
        for (int kt = 0; kt < 4; ++kt)
          afr[mt][kt] = ldg8(ys + (size_t)(mt * 16 + ln) * 128 + kt * 32 + q * 8);
#pragma unroll
      for (int mt = 0; mt < 4; ++mt) {
        f32x4 a8[8];
#pragma unroll
        for (int nt = 0; nt < 8; ++nt) a8[nt] = (f32x4){0.f, 0.f, 0.f, 0.f};
#pragma unroll
        for (int kt = 0; kt < 4; ++kt) {
#pragma unroll
          for (int nt = 0; nt < 8; ++nt)
            a8[nt] = __builtin_amdgcn_mfma_f32_16x16x32_bf16(afr[mt][kt], bfr[nt][kt], a8[nt], 0, 0, 0);
        }
#pragma unroll
        for (int nt = 0; nt < 8; ++nt)
#pragma unroll
          for (int r = 0; r < 4; ++r)
            xs[(size_t)(mt * 16 + q * 4 + r) * 512 + (w * 8 + nt) * 16 + ln] = (bf16_t)a8[nt][r];
      }
      __syncthreads();
      if (tid == 0) publish(my, (uint32_t)endk(k));
    }
  }
}

extern "C" void kernel_launch(void* const* d_in, const int* in_sizes, int n_in,
                              void* d_out, int out_size, void* d_ws, size_t ws_size,
                              hipStream_t stream) {
  (void)in_sizes; (void)n_in; (void)out_size; (void)ws_size;
  const float* inputs    = (const float*)d_in[0];
  const float* proj_w    = (const float*)d_in[4];
  const float* proj_b    = (const float*)d_in[5];
  const float* w_ih0     = (const float*)d_in[6];
  const float* w_hh0     = (const float*)d_in[7];
  const float* b_ih0     = (const float*)d_in[8];
  const float* b_hh0     = (const float*)d_in[9];
  const float* w_ih_rest = (const float*)d_in[10];
  const float* w_hh_rest = (const float*)d_in[11];
  const float* b_ih_rest = (const float*)d_in[12];
  const float* b_hh_rest = (const float*)d_in[13];
  const float* out_w     = (const float*)d_in[14];
  const float* out_b     = (const float*)d_in[15];
  uint8_t* ws = (uint8_t*)d_ws;
  float* out = (float*)d_out;

  k_prep_misc<<<dim3(2048), dim3(128), 0, stream>>>(w_hh0, w_ih_rest, w_hh_rest,
                                                    b_ih_rest, b_hh_rest, ws);
  k_prep_effw<<<dim3(512), dim3(256), 0, stream>>>(proj_w, proj_b, w_ih0, b_ih0, b_hh0, ws);
  k_pipeline<<<dim3(256), dim3(256), 0, stream>>>(inputs, out_w, out_b, out, ws);
}